// Round 5
// baseline (204.792 us; speedup 1.0000x reference)
//
#include <hip/hip_runtime.h>

typedef __bf16 bf16;
typedef __attribute__((ext_vector_type(8))) __bf16 bf16x8;
typedef __attribute__((ext_vector_type(2))) __bf16 bf16x2;
typedef __attribute__((ext_vector_type(4))) float f32x4;

#define AS1 __attribute__((address_space(1)))
#define AS3 __attribute__((address_space(3)))

// Problem constants
#define BB 2
#define SS 2048
#define DD 1024
#define HH 16
#define HD 64
#define BH (BB*HH)

// 0.125 (1/sqrt(64)) * 1/ln(2): folded into Q so scores come out in log2 units
#define QSCALE 0.1803368801111244f

static __device__ __forceinline__ f32x4 mfma16(bf16x8 a, bf16x8 b, f32x4 c) {
  return __builtin_amdgcn_mfma_f32_16x16x32_bf16(a, b, c, 0, 0, 0);
}
static __device__ __forceinline__ float fexp2(float x) {
  return __builtin_amdgcn_exp2f(x);
}

// XCD-aware remap, 512-block grids: all 16 blocks of a bh on one XCD.
static __device__ __forceinline__ void swz512(int bid, int& bh, int& pr) {
  int c = bid & 7, j = bid >> 3;
  bh = c + 8 * (j & 3);
  pr = j >> 2;
}
// XCD-aware remap, 1024-block grids: all 32 blocks of a bh on one XCD.
static __device__ __forceinline__ void swz1024(int bid, int& bh, int& strip0, int& qh) {
  int c = bid & 7, j = bid >> 3;
  bh = c + 8 * (j & 3);
  int rem = j >> 2;          // 0..31
  strip0 = rem & 15;
  qh = rem >> 4;
}

// ---------------- fp32 -> bf16 conversion, fused (weights: 4 tensors) ----------------
__global__ __launch_bounds__(256) void cvt_w(const float* __restrict__ s0, const float* __restrict__ s1,
                                             const float* __restrict__ s2, const float* __restrict__ s3,
                                             bf16* __restrict__ o0, bf16* __restrict__ o1,
                                             bf16* __restrict__ o2, bf16* __restrict__ o3) {
  const int z = blockIdx.y;
  const float* s = (z == 0) ? s0 : (z == 1) ? s1 : (z == 2) ? s2 : s3;
  bf16* o = (z == 0) ? o0 : (z == 1) ? o1 : (z == 2) ? o2 : o3;
  int i = blockIdx.x * 256 + threadIdx.x;
  const float4* sp = (const float4*)s;
  float4 a = sp[2 * i], b = sp[2 * i + 1];
  bf16x8 v;
  v[0] = (bf16)a.x; v[1] = (bf16)a.y; v[2] = (bf16)a.z; v[3] = (bf16)a.w;
  v[4] = (bf16)b.x; v[5] = (bf16)b.y; v[6] = (bf16)b.z; v[7] = (bf16)b.w;
  ((bf16x8*)o)[i] = v;
}

// ---------------- fp32 -> bf16 conversion, fused (inputs: 3 tensors) ----------------
__global__ __launch_bounds__(256) void cvt_x(const float* __restrict__ s0, const float* __restrict__ s1,
                                             const float* __restrict__ s2,
                                             bf16* __restrict__ o0, bf16* __restrict__ o1,
                                             bf16* __restrict__ o2) {
  const int z = blockIdx.y;
  const float* s = (z == 0) ? s0 : (z == 1) ? s1 : s2;
  bf16* o = (z == 0) ? o0 : (z == 1) ? o1 : o2;
  int i = blockIdx.x * 256 + threadIdx.x;
  const float4* sp = (const float4*)s;
  float4 a = sp[2 * i], b = sp[2 * i + 1];
  bf16x8 v;
  v[0] = (bf16)a.x; v[1] = (bf16)a.y; v[2] = (bf16)a.z; v[3] = (bf16)a.w;
  v[4] = (bf16)b.x; v[5] = (bf16)b.y; v[6] = (bf16)b.z; v[7] = (bf16)b.w;
  ((bf16x8*)o)[i] = v;
}

// ---------------- core 128x128 bf16 NT GEMM (C = A * B^T), K mult of 32 ----------------
__device__ __forceinline__ void gemm_core(const bf16* __restrict__ A,
                                          const bf16* __restrict__ Bm, int K,
                                          int m0, int n0, int w, int l,
                                          bf16* sA, bf16* sB, f32x4 (&acc)[4][4]) {
  const int l15 = l & 15, lg = l >> 4;
  const int wr = (w >> 1) * 64, wc = (w & 1) * 64;
  for (int kt = 0; kt < K; kt += 32) {
#pragma unroll
    for (int i = 0; i < 2; ++i) {
      int t = i * 256 + w * 64 + l;
      const bf16* ga = A + (size_t)(m0 + (t >> 2)) * K + kt + (t & 3) * 8;
      const bf16* gb = Bm + (size_t)(n0 + (t >> 2)) * K + kt + (t & 3) * 8;
      __builtin_amdgcn_global_load_lds((const AS1 void*)ga,
                                       (AS3 void*)(sA + (i * 256 + w * 64) * 8), 16, 0, 0);
      __builtin_amdgcn_global_load_lds((const AS1 void*)gb,
                                       (AS3 void*)(sB + (i * 256 + w * 64) * 8), 16, 0, 0);
    }
    __syncthreads();
    bf16x8 af[4], bfr[4];
#pragma unroll
    for (int m = 0; m < 4; ++m)
      af[m] = *(const bf16x8*)(sA + (wr + m * 16 + l15) * 32 + lg * 8);
#pragma unroll
    for (int n = 0; n < 4; ++n)
      bfr[n] = *(const bf16x8*)(sB + (wc + n * 16 + l15) * 32 + lg * 8);
#pragma unroll
    for (int m = 0; m < 4; ++m)
#pragma unroll
      for (int n = 0; n < 4; ++n)
        acc[m][n] = mfma16(af[m], bfr[n], acc[m][n]);
    __syncthreads();
  }
}

// ---------------- batched QKV projection: y = x @ W^T + b, heads layout ----------------
// z=0: Q (prescaled by QSCALE) -> [BH][S][64]; z=1: K -> [BH][S][64]; z=2: V -> [BH][64][S]
__global__ __launch_bounds__(256) void proj_gemm(
    const bf16* __restrict__ Xq, const bf16* __restrict__ Xk, const bf16* __restrict__ Xv,
    const bf16* __restrict__ Wq, const bf16* __restrict__ Wk, const bf16* __restrict__ Wv,
    const float* __restrict__ bq, const float* __restrict__ bk, const float* __restrict__ bv,
    bf16* __restrict__ Oq, bf16* __restrict__ Ok, bf16* __restrict__ Ovt) {
  __shared__ __align__(16) bf16 sA[128 * 32];
  __shared__ __align__(16) bf16 sB[128 * 32];
  const int z = blockIdx.z;
  const bf16* A = (z == 0) ? Xq : ((z == 1) ? Xk : Xv);
  const bf16* W = (z == 0) ? Wq : ((z == 1) ? Wk : Wv);
  const float* bias = (z == 0) ? bq : ((z == 1) ? bk : bv);
  const int tid = threadIdx.x, l = tid & 63, w = tid >> 6;
  const int m0 = blockIdx.y * 128, n0 = blockIdx.x * 128;
  f32x4 acc[4][4] = {};
  gemm_core(A, W, DD, m0, n0, w, l, sA, sB, acc);
  const int l15 = l & 15, lg = l >> 4;
  const int wr = (w >> 1) * 64, wc = (w & 1) * 64;
#pragma unroll
  for (int n = 0; n < 4; ++n) {
    int col = n0 + wc + n * 16 + l15;
    float bb = bias[col];
    int h = col >> 6, d = col & 63;
#pragma unroll
    for (int m = 0; m < 4; ++m) {
#pragma unroll
      for (int r = 0; r < 4; ++r) {
        int row = m0 + wr + m * 16 + lg * 4 + r;
        int b = row >> 11, s = row & (SS - 1);
        float vv = acc[m][n][r] + bb;
        if (z == 0) vv *= QSCALE;
        if (z != 2)
          ((z == 0) ? Oq : Ok)[(((size_t)(b * HH + h)) * SS + s) * HD + d] = (bf16)vv;
        else
          Ovt[(((size_t)(b * HH + h)) * HD + d) * SS + s] = (bf16)vv;
      }
    }
  }
}

// ---------------- output projection: out = ctx @ Wo^T + bo (fp32 out) ----------------
__global__ __launch_bounds__(256) void out_gemm(const bf16* __restrict__ A,
                                                const bf16* __restrict__ W,
                                                const float* __restrict__ bias,
                                                float* __restrict__ out) {
  __shared__ __align__(16) bf16 sA[128 * 32];
  __shared__ __align__(16) bf16 sB[128 * 32];
  const int tid = threadIdx.x, l = tid & 63, w = tid >> 6;
  const int m0 = blockIdx.y * 128, n0 = blockIdx.x * 128;
  f32x4 acc[4][4] = {};
  gemm_core(A, W, DD, m0, n0, w, l, sA, sB, acc);
  const int l15 = l & 15, lg = l >> 4;
  const int wr = (w >> 1) * 64, wc = (w & 1) * 64;
#pragma unroll
  for (int n = 0; n < 4; ++n) {
    int col = n0 + wc + n * 16 + l15;
    float bb = bias[col];
#pragma unroll
    for (int m = 0; m < 4; ++m)
#pragma unroll
      for (int r = 0; r < 4; ++r) {
        int row = m0 + wr + m * 16 + lg * 4 + r;
        out[(size_t)row * DD + col] = acc[m][n][r] + bb;
      }
  }
}

// ---------------- pass A: per-column partial softmax denominator -----------------------
// Grid 1024: (bh, strip-pair, q-half). 64 q rows / iteration: 8 batched Q loads,
// 4 independent 2-MFMA chains, 4 z accumulators -> latency-tolerant.
// zPart[qh][bh][col]; attn_ctx combines rz = 1/(z0+z1).
__global__ __launch_bounds__(256) void colz(const bf16* __restrict__ Qb,
                                            const bf16* __restrict__ Kb,
                                            float* __restrict__ zPart) {
  int bh, strip0, qh;
  swz1024(blockIdx.x, bh, strip0, qh);
  const int tid = threadIdx.x, l = tid & 63, w = tid >> 6;
  const int l15 = l & 15, lg = l >> 4;
  const bf16* Q = Qb + (size_t)bh * SS * HD;
  const bf16* Kh = Kb + (size_t)bh * SS * HD;
#pragma unroll
  for (int half = 0; half < 2; ++half) {
    const int strip = half ? (31 - strip0) : strip0;
    const int kw = strip * 64 + w * 16;
    bf16x8 kb0 = *(const bf16x8*)&Kh[(kw + l15) * HD + lg * 8];
    bf16x8 kb1 = *(const bf16x8*)&Kh[(kw + l15) * HD + 32 + lg * 8];
    const int kcol = kw + l15;
    f32x4 z = {};
    for (int qb = strip * 64 + qh * 64; qb < SS; qb += 128) {
      bf16x8 a[4][2];
#pragma unroll
      for (int t = 0; t < 4; ++t) {
        a[t][0] = *(const bf16x8*)&Q[(qb + t * 16 + l15) * HD + lg * 8];
        a[t][1] = *(const bf16x8*)&Q[(qb + t * 16 + l15) * HD + 32 + lg * 8];
      }
      f32x4 d[4] = {};
#pragma unroll
      for (int t = 0; t < 4; ++t) {
        d[t] = mfma16(a[t][0], kb0, d[t]);
        d[t] = mfma16(a[t][1], kb1, d[t]);
      }
#pragma unroll
      for (int t = 0; t < 4; ++t)
#pragma unroll
        for (int r = 0; r < 4; ++r) {
          int qq = qb + t * 16 + lg * 4 + r;
          z[t] += (qq > kcol) ? fexp2(d[t][r]) : 0.f;
        }
    }
    float zs = (z[0] + z[1]) + (z[2] + z[3]);
    zs += __shfl_xor(zs, 16);
    zs += __shfl_xor(zs, 32);
    if (l < 16) zPart[((size_t)qh * BH + bh) * SS + kcol] = zs;
  }
}

// ---------------- pass B: k-split across 4 waves + in-register pi-packed PV -------------
// Block handles q-tile pair (t, 31-t) of 64 rows (66 uniform k-chunks/block, ~16.5/wave).
// Swapped QK^T (mfma(K,Q)) -> lane holds P[q=l15][k] in-register; packed into the PV
// A-fragment under pi(8lg+j) = (j<4 ? 4lg+j : 16+4lg+j-4); V loads with the same pi.
// Per-wave 64q x 64d fp32 partials merged via single-sync 3-buffer LDS tree.
__global__ __launch_bounds__(256, 2) void attn_ctx(const bf16* __restrict__ Qb,
                                                   const bf16* __restrict__ Kb,
                                                   const bf16* __restrict__ Vt,
                                                   const float* __restrict__ zPart,
                                                   bf16* __restrict__ ctx) {
  __shared__ __align__(16) float red[3][64 * 68];  // [d][q] pitch 68
  int bh, pr;
  swz512(blockIdx.x, bh, pr);
  const int tid = threadIdx.x, l = tid & 63, w = tid >> 6;
  const int l15 = l & 15, lg = l >> 4;
  const bf16* Q = Qb + (size_t)bh * SS * HD;
  const bf16* Kh = Kb + (size_t)bh * SS * HD;
  const bf16* V = Vt + (size_t)bh * HD * SS;  // [64][S]
  const float* zp0 = zPart + (size_t)bh * SS;
  const float* zp1 = zPart + ((size_t)BH + bh) * SS;
  const int b = bh >> 4, h = bh & 15;

  // fully-masked column S-1 contributes uniform 1/S to every query row (used by wave 0)
  float vlast[4];
#pragma unroll
  for (int dt = 0; dt < 4; ++dt)
    vlast[dt] = (float)V[(size_t)(dt * 16 + l15) * SS + (SS - 1)] * (1.0f / (float)SS);

  for (int half = 0; half < 2; ++half) {
    const int t = half ? (31 - pr) : pr;
    const int q0 = t * 64;

    bf16x8 qa[4][2];
#pragma unroll
    for (int qt = 0; qt < 4; ++qt)
#pragma unroll
      for (int kk = 0; kk < 2; ++kk)
        qa[qt][kk] = *(const bf16x8*)&Q[(q0 + qt * 16 + l15) * HD + kk * 32 + lg * 8];

    f32x4 acc[4][4] = {};  // [qt][dt]
    const int kend = q0 + 64;
    for (int k0 = w * 32; k0 < kend; k0 += 128) {
      // K fragments for the two 16-row k tiles of this 32-k chunk
      bf16x8 ka0 = *(const bf16x8*)&Kh[(k0 + l15) * HD + lg * 8];
      bf16x8 ka1 = *(const bf16x8*)&Kh[(k0 + l15) * HD + 32 + lg * 8];
      bf16x8 kb0 = *(const bf16x8*)&Kh[(k0 + 16 + l15) * HD + lg * 8];
      bf16x8 kb1 = *(const bf16x8*)&Kh[(k0 + 16 + l15) * HD + 32 + lg * 8];
      // V fragments (pi order), independent of scores
      union { unsigned int u[4]; bf16x8 v; } vf[4];
#pragma unroll
      for (int dt = 0; dt < 4; ++dt) {
        const bf16* vrow = &V[(size_t)(dt * 16 + l15) * SS];
        uint2 lo = *(const uint2*)&vrow[k0 + 4 * lg];
        uint2 hi = *(const uint2*)&vrow[k0 + 16 + 4 * lg];
        vf[dt].u[0] = lo.x; vf[dt].u[1] = lo.y; vf[dt].u[2] = hi.x; vf[dt].u[3] = hi.y;
      }
      // rz[k] = 1/(z0[k]+z1[k]), element r -> k = k0 + kt*16 + lg*4 + r
      f32x4 za0 = *(const f32x4*)&zp0[k0 + lg * 4];
      f32x4 zb0 = *(const f32x4*)&zp1[k0 + lg * 4];
      f32x4 za1 = *(const f32x4*)&zp0[k0 + 16 + lg * 4];
      f32x4 zb1 = *(const f32x4*)&zp1[k0 + 16 + lg * 4];
      f32x4 rz0, rz1;
#pragma unroll
      for (int r = 0; r < 4; ++r) {
        float s0 = za0[r] + zb0[r], s1 = za1[r] + zb1[r];
        rz0[r] = (s0 > 0.f) ? 1.0f / s0 : 0.f;
        rz1[r] = (s1 > 0.f) ? 1.0f / s1 : 0.f;
      }
      // swapped scores: s[qt][kt] element r = S'[k=k0+kt*16+lg*4+r][q=q0+qt*16+l15]
      f32x4 s[4][2];
#pragma unroll
      for (int qt = 0; qt < 4; ++qt) {
        f32x4 z0 = {}, z1 = {};
        z0 = mfma16(ka0, qa[qt][0], z0);
        z0 = mfma16(ka1, qa[qt][1], z0);
        z1 = mfma16(kb0, qa[qt][0], z1);
        z1 = mfma16(kb1, qa[qt][1], z1);
        s[qt][0] = z0; s[qt][1] = z1;
      }
      const int kb0i = k0 + lg * 4, kb1i = k0 + 16 + lg * 4;
#pragma unroll
      for (int qt = 0; qt < 4; ++qt) {
        const int qq = q0 + qt * 16 + l15;
        union { unsigned int u[4]; bf16x8 v; } pa;
#pragma unroll
        for (int hw = 0; hw < 2; ++hw) {
          bf16x2 t0, t1;
#pragma unroll
          for (int r = 0; r < 2; ++r) {
            int rr = hw * 2 + r;
            float p0 = fexp2(s[qt][0][rr]) * ((kb0i + rr < qq) ? rz0[rr] : 0.f);
            float p1 = fexp2(s[qt][1][rr]) * ((kb1i + rr < qq) ? rz1[rr] : 0.f);
            t0[r] = (bf16)p0;
            t1[r] = (bf16)p1;
          }
          pa.u[hw] = __builtin_bit_cast(unsigned int, t0);
          pa.u[hw + 2] = __builtin_bit_cast(unsigned int, t1);
        }
#pragma unroll
        for (int dt = 0; dt < 4; ++dt)
          acc[qt][dt] = mfma16(pa.v, vf[dt].v, acc[qt][dt]);
      }
    }

    // merge the 4 per-wave partials: waves 1..3 stash, wave 0 combines + writes
    if (w) {
      float* buf = red[w - 1];
#pragma unroll
      for (int qt = 0; qt < 4; ++qt)
#pragma unroll
        for (int dt = 0; dt < 4; ++dt)
          *(f32x4*)&buf[(dt * 16 + l15) * 68 + qt * 16 + lg * 4] = acc[qt][dt];
    }
    __syncthreads();
    if (w == 0) {
#pragma unroll
      for (int qt = 0; qt < 4; ++qt) {
#pragma unroll
        for (int dt = 0; dt < 4; ++dt) {
          f32x4 a = acc[qt][dt];
#pragma unroll
          for (int j = 0; j < 3; ++j)
            a += *(const f32x4*)&red[j][(dt * 16 + l15) * 68 + qt * 16 + lg * 4];
#pragma unroll
          for (int r = 0; r < 4; ++r) {
            int q = q0 + qt * 16 + lg * 4 + r;
            ctx[((size_t)(b * SS + q)) * DD + h * HD + dt * 16 + l15] =
                (bf16)(a[r] + vlast[dt]);
          }
        }
      }
    }
    __syncthreads();  // protect red before next half reuses it
  }
}

// ---------------- launcher ----------------
extern "C" void kernel_launch(void* const* d_in, const int* in_sizes, int n_in,
                              void* d_out, int out_size, void* d_ws, size_t ws_size,
                              hipStream_t stream) {
  const float* q  = (const float*)d_in[0];
  const float* k  = (const float*)d_in[1];
  const float* v  = (const float*)d_in[2];
  const float* Wq = (const float*)d_in[3];
  const float* bq = (const float*)d_in[4];
  const float* Wk = (const float*)d_in[5];
  const float* bk = (const float*)d_in[6];
  const float* Wv = (const float*)d_in[7];
  const float* bv = (const float*)d_in[8];
  const float* Wo = (const float*)d_in[9];
  const float* bo = (const float*)d_in[10];

  char* ws = (char*)d_ws;
  const size_t SZP = (size_t)4096 * 1024 * 2;  // 8 MiB
  const size_t SZW = (size_t)1024 * 1024 * 2;  // 2 MiB
  bf16* Qb   = (bf16*)(ws + 0 * SZP);          // [BH][S][64] (prescaled)
  bf16* Kb   = (bf16*)(ws + 1 * SZP);          // [BH][S][64]
  bf16* Vt   = (bf16*)(ws + 2 * SZP);          // [BH][64][S]
  bf16* ctxb = (bf16*)(ws + 3 * SZP);          // [B][S][D]
  bf16* qb16 = (bf16*)(ws + 4 * SZP);
  bf16* kb16 = (bf16*)(ws + 5 * SZP);
  bf16* vb16 = (bf16*)(ws + 6 * SZP);
  bf16* Wqb  = (bf16*)(ws + 7 * SZP + 0 * SZW);
  bf16* Wkb  = (bf16*)(ws + 7 * SZP + 1 * SZW);
  bf16* Wvb  = (bf16*)(ws + 7 * SZP + 2 * SZW);
  bf16* Wob  = (bf16*)(ws + 7 * SZP + 3 * SZW);
  float* zPart = (float*)(ws + 7 * SZP + 4 * SZW);  // [2][BH][SS] fp32

  cvt_w<<<dim3(512, 4), 256, 0, stream>>>(Wq, Wk, Wv, Wo, Wqb, Wkb, Wvb, Wob);
  cvt_x<<<dim3(2048, 3), 256, 0, stream>>>(q, k, v, qb16, kb16, vb16);

  proj_gemm<<<dim3(1024 / 128, 4096 / 128, 3), 256, 0, stream>>>(
      qb16, kb16, vb16, Wqb, Wkb, Wvb, bq, bk, bv, Qb, Kb, Vt);

  colz<<<1024, 256, 0, stream>>>(Qb, Kb, zPart);
  attn_ctx<<<512, 256, 0, stream>>>(Qb, Kb, Vt, zPart, ctxb);

  out_gemm<<<dim3(1024 / 128, 4096 / 128), 256, 0, stream>>>(ctxb, Wob, bo, (float*)d_out);
}

// Round 6
// 170.299 us; speedup vs baseline: 1.2025x; 1.2025x over previous
//
#include <hip/hip_runtime.h>

typedef __bf16 bf16;
typedef __attribute__((ext_vector_type(8))) __bf16 bf16x8;
typedef __attribute__((ext_vector_type(2))) __bf16 bf16x2;
typedef __attribute__((ext_vector_type(4))) float f32x4;

#define AS1 __attribute__((address_space(1)))
#define AS3 __attribute__((address_space(3)))

// Problem constants
#define BB 2
#define SS 2048
#define DD 1024
#define HH 16
#define HD 64
#define BH (BB*HH)

// 0.125 (1/sqrt(64)) * 1/ln(2): folded into Q so scores come out in log2 units
#define QSCALE 0.1803368801111244f

static __device__ __forceinline__ f32x4 mfma16(bf16x8 a, bf16x8 b, f32x4 c) {
  return __builtin_amdgcn_mfma_f32_16x16x32_bf16(a, b, c, 0, 0, 0);
}
static __device__ __forceinline__ float fexp2(float x) {
  return __builtin_amdgcn_exp2f(x);
}

// XCD-aware remap, 512-block grids: all 16 blocks of a bh on one XCD.
static __device__ __forceinline__ void swz512(int bid, int& bh, int& pr) {
  int c = bid & 7, j = bid >> 3;
  bh = c + 8 * (j & 3);
  pr = j >> 2;
}
// XCD-aware remap, 1024-block grids: all 32 blocks of a bh on one XCD.
static __device__ __forceinline__ void swz1024(int bid, int& bh, int& strip0, int& qh) {
  int c = bid & 7, j = bid >> 3;
  bh = c + 8 * (j & 3);
  int rem = j >> 2;          // 0..31
  strip0 = rem & 15;
  qh = rem >> 4;
}

// ---------------- fp32 -> bf16 conversion, fused (weights: 4 tensors) ----------------
__global__ __launch_bounds__(256) void cvt_w(const float* __restrict__ s0, const float* __restrict__ s1,
                                             const float* __restrict__ s2, const float* __restrict__ s3,
                                             bf16* __restrict__ o0, bf16* __restrict__ o1,
                                             bf16* __restrict__ o2, bf16* __restrict__ o3) {
  const int z = blockIdx.y;
  const float* s = (z == 0) ? s0 : (z == 1) ? s1 : (z == 2) ? s2 : s3;
  bf16* o = (z == 0) ? o0 : (z == 1) ? o1 : (z == 2) ? o2 : o3;
  int i = blockIdx.x * 256 + threadIdx.x;
  const float4* sp = (const float4*)s;
  float4 a = sp[2 * i], b = sp[2 * i + 1];
  bf16x8 v;
  v[0] = (bf16)a.x; v[1] = (bf16)a.y; v[2] = (bf16)a.z; v[3] = (bf16)a.w;
  v[4] = (bf16)b.x; v[5] = (bf16)b.y; v[6] = (bf16)b.z; v[7] = (bf16)b.w;
  ((bf16x8*)o)[i] = v;
}

// ---------------- fp32 -> bf16 conversion, fused (inputs: 3 tensors) ----------------
__global__ __launch_bounds__(256) void cvt_x(const float* __restrict__ s0, const float* __restrict__ s1,
                                             const float* __restrict__ s2,
                                             bf16* __restrict__ o0, bf16* __restrict__ o1,
                                             bf16* __restrict__ o2) {
  const int z = blockIdx.y;
  const float* s = (z == 0) ? s0 : (z == 1) ? s1 : s2;
  bf16* o = (z == 0) ? o0 : (z == 1) ? o1 : o2;
  int i = blockIdx.x * 256 + threadIdx.x;
  const float4* sp = (const float4*)s;
  float4 a = sp[2 * i], b = sp[2 * i + 1];
  bf16x8 v;
  v[0] = (bf16)a.x; v[1] = (bf16)a.y; v[2] = (bf16)a.z; v[3] = (bf16)a.w;
  v[4] = (bf16)b.x; v[5] = (bf16)b.y; v[6] = (bf16)b.z; v[7] = (bf16)b.w;
  ((bf16x8*)o)[i] = v;
}

// ---------------- core 128x128 bf16 NT GEMM (C = A * B^T), K mult of 32 ----------------
__device__ __forceinline__ void gemm_core(const bf16* __restrict__ A,
                                          const bf16* __restrict__ Bm, int K,
                                          int m0, int n0, int w, int l,
                                          bf16* sA, bf16* sB, f32x4 (&acc)[4][4]) {
  const int l15 = l & 15, lg = l >> 4;
  const int wr = (w >> 1) * 64, wc = (w & 1) * 64;
  for (int kt = 0; kt < K; kt += 32) {
#pragma unroll
    for (int i = 0; i < 2; ++i) {
      int t = i * 256 + w * 64 + l;
      const bf16* ga = A + (size_t)(m0 + (t >> 2)) * K + kt + (t & 3) * 8;
      const bf16* gb = Bm + (size_t)(n0 + (t >> 2)) * K + kt + (t & 3) * 8;
      __builtin_amdgcn_global_load_lds((const AS1 void*)ga,
                                       (AS3 void*)(sA + (i * 256 + w * 64) * 8), 16, 0, 0);
      __builtin_amdgcn_global_load_lds((const AS1 void*)gb,
                                       (AS3 void*)(sB + (i * 256 + w * 64) * 8), 16, 0, 0);
    }
    __syncthreads();
    bf16x8 af[4], bfr[4];
#pragma unroll
    for (int m = 0; m < 4; ++m)
      af[m] = *(const bf16x8*)(sA + (wr + m * 16 + l15) * 32 + lg * 8);
#pragma unroll
    for (int n = 0; n < 4; ++n)
      bfr[n] = *(const bf16x8*)(sB + (wc + n * 16 + l15) * 32 + lg * 8);
#pragma unroll
    for (int m = 0; m < 4; ++m)
#pragma unroll
      for (int n = 0; n < 4; ++n)
        acc[m][n] = mfma16(af[m], bfr[n], acc[m][n]);
    __syncthreads();
  }
}

// ---------------- batched QKV projection: y = x @ W^T + b, heads layout ----------------
// z=0: Q (prescaled by QSCALE) -> [BH][S][64]; z=1: K -> [BH][S][64]; z=2: V -> [BH][64][S]
__global__ __launch_bounds__(256) void proj_gemm(
    const bf16* __restrict__ Xq, const bf16* __restrict__ Xk, const bf16* __restrict__ Xv,
    const bf16* __restrict__ Wq, const bf16* __restrict__ Wk, const bf16* __restrict__ Wv,
    const float* __restrict__ bq, const float* __restrict__ bk, const float* __restrict__ bv,
    bf16* __restrict__ Oq, bf16* __restrict__ Ok, bf16* __restrict__ Ovt) {
  __shared__ __align__(16) bf16 sA[128 * 32];
  __shared__ __align__(16) bf16 sB[128 * 32];
  const int z = blockIdx.z;
  const bf16* A = (z == 0) ? Xq : ((z == 1) ? Xk : Xv);
  const bf16* W = (z == 0) ? Wq : ((z == 1) ? Wk : Wv);
  const float* bias = (z == 0) ? bq : ((z == 1) ? bk : bv);
  const int tid = threadIdx.x, l = tid & 63, w = tid >> 6;
  const int m0 = blockIdx.y * 128, n0 = blockIdx.x * 128;
  f32x4 acc[4][4] = {};
  gemm_core(A, W, DD, m0, n0, w, l, sA, sB, acc);
  const int l15 = l & 15, lg = l >> 4;
  const int wr = (w >> 1) * 64, wc = (w & 1) * 64;
#pragma unroll
  for (int n = 0; n < 4; ++n) {
    int col = n0 + wc + n * 16 + l15;
    float bb = bias[col];
    int h = col >> 6, d = col & 63;
#pragma unroll
    for (int m = 0; m < 4; ++m) {
#pragma unroll
      for (int r = 0; r < 4; ++r) {
        int row = m0 + wr + m * 16 + lg * 4 + r;
        int b = row >> 11, s = row & (SS - 1);
        float vv = acc[m][n][r] + bb;
        if (z == 0) vv *= QSCALE;
        if (z != 2)
          ((z == 0) ? Oq : Ok)[(((size_t)(b * HH + h)) * SS + s) * HD + d] = (bf16)vv;
        else
          Ovt[(((size_t)(b * HH + h)) * HD + d) * SS + s] = (bf16)vv;
      }
    }
  }
}

// ---------------- output projection: out = ctx @ Wo^T + bo (fp32 out) ----------------
__global__ __launch_bounds__(256) void out_gemm(const bf16* __restrict__ A,
                                                const bf16* __restrict__ W,
                                                const float* __restrict__ bias,
                                                float* __restrict__ out) {
  __shared__ __align__(16) bf16 sA[128 * 32];
  __shared__ __align__(16) bf16 sB[128 * 32];
  const int tid = threadIdx.x, l = tid & 63, w = tid >> 6;
  const int m0 = blockIdx.y * 128, n0 = blockIdx.x * 128;
  f32x4 acc[4][4] = {};
  gemm_core(A, W, DD, m0, n0, w, l, sA, sB, acc);
  const int l15 = l & 15, lg = l >> 4;
  const int wr = (w >> 1) * 64, wc = (w & 1) * 64;
#pragma unroll
  for (int n = 0; n < 4; ++n) {
    int col = n0 + wc + n * 16 + l15;
    float bb = bias[col];
#pragma unroll
    for (int m = 0; m < 4; ++m)
#pragma unroll
      for (int r = 0; r < 4; ++r) {
        int row = m0 + wr + m * 16 + lg * 4 + r;
        out[(size_t)row * DD + col] = acc[m][n][r] + bb;
      }
  }
}

// ---------------- pass A: per-column partial softmax denominator -----------------------
// Block owns a 64-column strip-pair (s, 31-s); all 8 K fragments held in registers.
// The 4 waves take INTERLEAVED 16-row Q tiles (disjoint addresses -> 4x MLP), with
// double-buffered Q prefetch; per-wave partial column sums merged via LDS once per half.
// zPart[qh][bh][col]; attn_ctx combines rz = 1/(z0+z1).
__global__ __launch_bounds__(256) void colz(const bf16* __restrict__ Qb,
                                            const bf16* __restrict__ Kb,
                                            float* __restrict__ zPart) {
  __shared__ float zred[4][64];
  int bh, pair, qh;
  swz1024(blockIdx.x, bh, pair, qh);
  const int tid = threadIdx.x, l = tid & 63, w = tid >> 6;
  const int l15 = l & 15, lg = l >> 4;
  const bf16* Q = Qb + (size_t)bh * SS * HD;
  const bf16* Kh = Kb + (size_t)bh * SS * HD;

  for (int half = 0; half < 2; ++half) {
    const int s = half ? (31 - pair) : pair;
    const int c0 = s * 64;
    // 8 K fragments: 64 columns, resident for the whole half
    bf16x8 kf[4][2];
#pragma unroll
    for (int kt = 0; kt < 4; ++kt) {
      kf[kt][0] = *(const bf16x8*)&Kh[(c0 + kt * 16 + l15) * HD + lg * 8];
      kf[kt][1] = *(const bf16x8*)&Kh[(c0 + kt * 16 + l15) * HD + 32 + lg * 8];
    }
    float z[4] = {};
    const int qstart = c0 + qh * 64 + w * 16;  // this wave's first 16-row tile
    bf16x8 qa0, qa1, qn0, qn1;
    if (qstart < SS) {
      qa0 = *(const bf16x8*)&Q[(qstart + l15) * HD + lg * 8];
      qa1 = *(const bf16x8*)&Q[(qstart + l15) * HD + 32 + lg * 8];
    }
    for (int qb = qstart; qb < SS; qb += 128) {
      const int qnext = qb + 128;
      if (qnext < SS) {  // prefetch next tile while current computes
        qn0 = *(const bf16x8*)&Q[(qnext + l15) * HD + lg * 8];
        qn1 = *(const bf16x8*)&Q[(qnext + l15) * HD + 32 + lg * 8];
      }
      f32x4 d[4] = {};
#pragma unroll
      for (int kt = 0; kt < 4; ++kt) {
        d[kt] = mfma16(qa0, kf[kt][0], d[kt]);
        d[kt] = mfma16(qa1, kf[kt][1], d[kt]);
      }
#pragma unroll
      for (int kt = 0; kt < 4; ++kt) {
        const int kcol = c0 + kt * 16 + l15;
#pragma unroll
        for (int r = 0; r < 4; ++r) {
          int qq = qb + lg * 4 + r;
          z[kt] += (qq > kcol) ? fexp2(d[kt][r]) : 0.f;
        }
      }
      qa0 = qn0; qa1 = qn1;
    }
    // reduce the 4 lane-groups (each saw different q rows of this wave's tiles)
#pragma unroll
    for (int kt = 0; kt < 4; ++kt) {
      z[kt] += __shfl_xor(z[kt], 16);
      z[kt] += __shfl_xor(z[kt], 32);
    }
    if (l < 16) {
#pragma unroll
      for (int kt = 0; kt < 4; ++kt) zred[w][kt * 16 + l15] = z[kt];
    }
    __syncthreads();
    if (tid < 64) {
      float zs = zred[0][tid] + zred[1][tid] + zred[2][tid] + zred[3][tid];
      zPart[((size_t)qh * BH + bh) * SS + c0 + tid] = zs;
    }
    __syncthreads();  // protect zred before second half
  }
}

// ---------------- pass B: k-split across 4 waves + in-register pi-packed PV -------------
// Block handles q-tile pair (t, 31-t) of 64 rows (66 uniform k-chunks/block, ~16.5/wave).
// Swapped QK^T (mfma(K,Q)) -> lane holds P[q=l15][k] in-register; packed into the PV
// A-fragment under pi(8lg+j) = (j<4 ? 4lg+j : 16+4lg+j-4); V loads with the same pi.
// Per-wave 64q x 64d fp32 partials merged via single-sync 3-buffer LDS tree.
__global__ __launch_bounds__(256, 2) void attn_ctx(const bf16* __restrict__ Qb,
                                                   const bf16* __restrict__ Kb,
                                                   const bf16* __restrict__ Vt,
                                                   const float* __restrict__ zPart,
                                                   bf16* __restrict__ ctx) {
  __shared__ __align__(16) float red[3][64 * 68];  // [d][q] pitch 68
  int bh, pr;
  swz512(blockIdx.x, bh, pr);
  const int tid = threadIdx.x, l = tid & 63, w = tid >> 6;
  const int l15 = l & 15, lg = l >> 4;
  const bf16* Q = Qb + (size_t)bh * SS * HD;
  const bf16* Kh = Kb + (size_t)bh * SS * HD;
  const bf16* V = Vt + (size_t)bh * HD * SS;  // [64][S]
  const float* zp0 = zPart + (size_t)bh * SS;
  const float* zp1 = zPart + ((size_t)BH + bh) * SS;
  const int b = bh >> 4, h = bh & 15;

  // fully-masked column S-1 contributes uniform 1/S to every query row (used by wave 0)
  float vlast[4];
#pragma unroll
  for (int dt = 0; dt < 4; ++dt)
    vlast[dt] = (float)V[(size_t)(dt * 16 + l15) * SS + (SS - 1)] * (1.0f / (float)SS);

  for (int half = 0; half < 2; ++half) {
    const int t = half ? (31 - pr) : pr;
    const int q0 = t * 64;

    bf16x8 qa[4][2];
#pragma unroll
    for (int qt = 0; qt < 4; ++qt)
#pragma unroll
      for (int kk = 0; kk < 2; ++kk)
        qa[qt][kk] = *(const bf16x8*)&Q[(q0 + qt * 16 + l15) * HD + kk * 32 + lg * 8];

    f32x4 acc[4][4] = {};  // [qt][dt]
    const int kend = q0 + 64;
    for (int k0 = w * 32; k0 < kend; k0 += 128) {
      // K fragments for the two 16-row k tiles of this 32-k chunk
      bf16x8 ka0 = *(const bf16x8*)&Kh[(k0 + l15) * HD + lg * 8];
      bf16x8 ka1 = *(const bf16x8*)&Kh[(k0 + l15) * HD + 32 + lg * 8];
      bf16x8 kb0 = *(const bf16x8*)&Kh[(k0 + 16 + l15) * HD + lg * 8];
      bf16x8 kb1 = *(const bf16x8*)&Kh[(k0 + 16 + l15) * HD + 32 + lg * 8];
      // V fragments (pi order), independent of scores
      union { unsigned int u[4]; bf16x8 v; } vf[4];
#pragma unroll
      for (int dt = 0; dt < 4; ++dt) {
        const bf16* vrow = &V[(size_t)(dt * 16 + l15) * SS];
        uint2 lo = *(const uint2*)&vrow[k0 + 4 * lg];
        uint2 hi = *(const uint2*)&vrow[k0 + 16 + 4 * lg];
        vf[dt].u[0] = lo.x; vf[dt].u[1] = lo.y; vf[dt].u[2] = hi.x; vf[dt].u[3] = hi.y;
      }
      // rz[k] = 1/(z0[k]+z1[k]), element r -> k = k0 + kt*16 + lg*4 + r
      f32x4 za0 = *(const f32x4*)&zp0[k0 + lg * 4];
      f32x4 zb0 = *(const f32x4*)&zp1[k0 + lg * 4];
      f32x4 za1 = *(const f32x4*)&zp0[k0 + 16 + lg * 4];
      f32x4 zb1 = *(const f32x4*)&zp1[k0 + 16 + lg * 4];
      f32x4 rz0, rz1;
#pragma unroll
      for (int r = 0; r < 4; ++r) {
        float s0 = za0[r] + zb0[r], s1 = za1[r] + zb1[r];
        rz0[r] = (s0 > 0.f) ? 1.0f / s0 : 0.f;
        rz1[r] = (s1 > 0.f) ? 1.0f / s1 : 0.f;
      }
      // swapped scores: s[qt][kt] element r = S'[k=k0+kt*16+lg*4+r][q=q0+qt*16+l15]
      f32x4 s[4][2];
#pragma unroll
      for (int qt = 0; qt < 4; ++qt) {
        f32x4 z0 = {}, z1 = {};
        z0 = mfma16(ka0, qa[qt][0], z0);
        z0 = mfma16(ka1, qa[qt][1], z0);
        z1 = mfma16(kb0, qa[qt][0], z1);
        z1 = mfma16(kb1, qa[qt][1], z1);
        s[qt][0] = z0; s[qt][1] = z1;
      }
      const int kb0i = k0 + lg * 4, kb1i = k0 + 16 + lg * 4;
#pragma unroll
      for (int qt = 0; qt < 4; ++qt) {
        const int qq = q0 + qt * 16 + l15;
        union { unsigned int u[4]; bf16x8 v; } pa;
#pragma unroll
        for (int hw = 0; hw < 2; ++hw) {
          bf16x2 t0, t1;
#pragma unroll
          for (int r = 0; r < 2; ++r) {
            int rr = hw * 2 + r;
            float p0 = fexp2(s[qt][0][rr]) * ((kb0i + rr < qq) ? rz0[rr] : 0.f);
            float p1 = fexp2(s[qt][1][rr]) * ((kb1i + rr < qq) ? rz1[rr] : 0.f);
            t0[r] = (bf16)p0;
            t1[r] = (bf16)p1;
          }
          pa.u[hw] = __builtin_bit_cast(unsigned int, t0);
          pa.u[hw + 2] = __builtin_bit_cast(unsigned int, t1);
        }
#pragma unroll
        for (int dt = 0; dt < 4; ++dt)
          acc[qt][dt] = mfma16(pa.v, vf[dt].v, acc[qt][dt]);
      }
    }

    // merge the 4 per-wave partials: waves 1..3 stash, wave 0 combines + writes
    if (w) {
      float* buf = red[w - 1];
#pragma unroll
      for (int qt = 0; qt < 4; ++qt)
#pragma unroll
        for (int dt = 0; dt < 4; ++dt)
          *(f32x4*)&buf[(dt * 16 + l15) * 68 + qt * 16 + lg * 4] = acc[qt][dt];
    }
    __syncthreads();
    if (w == 0) {
#pragma unroll
      for (int qt = 0; qt < 4; ++qt) {
#pragma unroll
        for (int dt = 0; dt < 4; ++dt) {
          f32x4 a = acc[qt][dt];
#pragma unroll
          for (int j = 0; j < 3; ++j)
            a += *(const f32x4*)&red[j][(dt * 16 + l15) * 68 + qt * 16 + lg * 4];
#pragma unroll
          for (int r = 0; r < 4; ++r) {
            int q = q0 + qt * 16 + lg * 4 + r;
            ctx[((size_t)(b * SS + q)) * DD + h * HD + dt * 16 + l15] =
                (bf16)(a[r] + vlast[dt]);
          }
        }
      }
    }
    __syncthreads();  // protect red before next half reuses it
  }
}

// ---------------- launcher ----------------
extern "C" void kernel_launch(void* const* d_in, const int* in_sizes, int n_in,
                              void* d_out, int out_size, void* d_ws, size_t ws_size,
                              hipStream_t stream) {
  const float* q  = (const float*)d_in[0];
  const float* k  = (const float*)d_in[1];
  const float* v  = (const float*)d_in[2];
  const float* Wq = (const float*)d_in[3];
  const float* bq = (const float*)d_in[4];
  const float* Wk = (const float*)d_in[5];
  const float* bk = (const float*)d_in[6];
  const float* Wv = (const float*)d_in[7];
  const float* bv = (const float*)d_in[8];
  const float* Wo = (const float*)d_in[9];
  const float* bo = (const float*)d_in[10];

  char* ws = (char*)d_ws;
  const size_t SZP = (size_t)4096 * 1024 * 2;  // 8 MiB
  const size_t SZW = (size_t)1024 * 1024 * 2;  // 2 MiB
  bf16* Qb   = (bf16*)(ws + 0 * SZP);          // [BH][S][64] (prescaled)
  bf16* Kb   = (bf16*)(ws + 1 * SZP);          // [BH][S][64]
  bf16* Vt   = (bf16*)(ws + 2 * SZP);          // [BH][64][S]
  bf16* ctxb = (bf16*)(ws + 3 * SZP);          // [B][S][D]
  bf16* qb16 = (bf16*)(ws + 4 * SZP);
  bf16* kb16 = (bf16*)(ws + 5 * SZP);
  bf16* vb16 = (bf16*)(ws + 6 * SZP);
  bf16* Wqb  = (bf16*)(ws + 7 * SZP + 0 * SZW);
  bf16* Wkb  = (bf16*)(ws + 7 * SZP + 1 * SZW);
  bf16* Wvb  = (bf16*)(ws + 7 * SZP + 2 * SZW);
  bf16* Wob  = (bf16*)(ws + 7 * SZP + 3 * SZW);
  float* zPart = (float*)(ws + 7 * SZP + 4 * SZW);  // [2][BH][SS] fp32

  cvt_w<<<dim3(512, 4), 256, 0, stream>>>(Wq, Wk, Wv, Wo, Wqb, Wkb, Wvb, Wob);
  cvt_x<<<dim3(2048, 3), 256, 0, stream>>>(q, k, v, qb16, kb16, vb16);

  proj_gemm<<<dim3(1024 / 128, 4096 / 128, 3), 256, 0, stream>>>(
      qb16, kb16, vb16, Wqb, Wkb, Wvb, bq, bk, bv, Qb, Kb, Vt);

  colz<<<1024, 256, 0, stream>>>(Qb, Kb, zPart);
  attn_ctx<<<512, 256, 0, stream>>>(Qb, Kb, Vt, zPart, ctxb);

  out_gemm<<<dim3(1024 / 128, 4096 / 128), 256, 0, stream>>>(ctxb, Wob, bo, (float*)d_out);
}